// Round 4
// baseline (112.196 us; speedup 1.0000x reference)
//
#include <hip/hip_runtime.h>
#include <hip/hip_bf16.h>
#include <math.h>

// Problem constants (fixed by setup_inputs)
constexpr int N   = 8192;
constexpr int D   = 128;
constexpr int IPC = 512;
constexpr int BZ  = 8192;
constexpr int Q0  = BZ - IPC;        // 7680: first query row
constexpr int NQ  = IPC;             // 512 queries
constexpr int JMAX = BZ - IPC;       // 7680 candidate cols [0,7680)
constexpr int JBLK = 128;            // j per block
constexpr int NJB  = JMAX / JBLK;    // 60
constexpr int EASY_JB = (2 * IPC) / JBLK;  // 8 -> jblk 0..7 easy ([0,1024)), 8..59 hard
constexpr int QBLK = 64;             // q per block
constexpr int NQB  = NQ / QBLK;      // 8
constexpr int NBLOCKS = NJB * NQB;   // 480
constexpr int RSTR = 136;            // LDS row stride in shorts (68 words = 4 mod 32 banks)

typedef __attribute__((ext_vector_type(8))) short short8;   // 8 bf16 = 4 VGPRs
typedef __attribute__((ext_vector_type(4))) float f32x4;    // MFMA C/D

// Fused: normalize (into LDS) + MFMA 64q x 128j tile + segmented j-max + last-block
// final softplus reduction. grid (NJB, NQB), 256 threads = 4 waves.
__global__ __launch_bounds__(256) void kmain(const float* __restrict__ f,
                                             const float* __restrict__ a_in,
                                             float* __restrict__ pm,
                                             unsigned* __restrict__ cnt,
                                             float* __restrict__ out) {
    __shared__ __align__(16) short S[192 * RSTR];   // rows 0..63 = A(q), 64..191 = B(j); 51 KB
    __shared__ float red[4][QBLK];
    __shared__ int isLast;
    __shared__ float wsum[4];

    const int tid  = threadIdx.x;
    const int lane = tid & 63;
    const int wv   = tid >> 6;
    const int jblk = blockIdx.x;           // 0..59
    const int qblk = blockIdx.y;           // 0..7

    // ---- Phase 1: normalize 192 rows -> bf16 LDS. 16 threads/row, 8 elems/thread.
    {
        const int sub = tid & 15;          // element group: elems [8*sub, 8*sub+8)
        const int rof = tid >> 4;          // row-within-group-of-16
        #pragma unroll
        for (int i = 0; i < 12; ++i) {
            int ridx = i * 16 + rof;       // 0..191
            int grow = (ridx < QBLK) ? (Q0 + qblk * QBLK + ridx)
                                     : (jblk * JBLK + (ridx - QBLK));
            const float* rp = f + (size_t)grow * D + sub * 8;
            float4 v0 = *(const float4*)(rp);
            float4 v1 = *(const float4*)(rp + 4);
            float ss = v0.x*v0.x + v0.y*v0.y + v0.z*v0.z + v0.w*v0.w
                     + v1.x*v1.x + v1.y*v1.y + v1.z*v1.z + v1.w*v1.w;
            #pragma unroll
            for (int off = 1; off < 16; off <<= 1) ss += __shfl_xor(ss, off, 64);
            float r = 1.0f / fmaxf(sqrtf(ss), 1e-12f);
            float sc[8] = { v0.x*r, v0.y*r, v0.z*r, v0.w*r,
                            v1.x*r, v1.y*r, v1.z*r, v1.w*r };
            short8 h;
            #pragma unroll
            for (int e = 0; e < 8; ++e) {
                __hip_bfloat16 b = __float2bfloat16(sc[e]);
                h[e] = *(short*)&b;
            }
            *(short8*)&S[ridx * RSTR + sub * 8] = h;
        }
    }
    __syncthreads();

    // ---- Phase 2: MFMA. Wave wv owns j sub-range [wv*32, wv*32+32).
    // 16x16x32 operand layout: lane l holds row (l&15), k = (l>>4)*8..+7.
    const int row16 = lane & 15;
    const int kgrp  = lane >> 4;           // 0..3
    const short* As = S;
    const short* Bs = S + QBLK * RSTR + wv * 32 * RSTR;

    f32x4 acc[4][2] = {};  // [q-group g][j-tile t]
    #pragma unroll
    for (int c = 0; c < 4; ++c) {          // k-chunks of 32
        const int ko = c * 32 + kgrp * 8;
        short8 a[4], b[2];
        #pragma unroll
        for (int g = 0; g < 4; ++g)
            a[g] = *(const short8*)(As + (g * 16 + row16) * RSTR + ko);
        #pragma unroll
        for (int t = 0; t < 2; ++t)
            b[t] = *(const short8*)(Bs + (t * 16 + row16) * RSTR + ko);
        #pragma unroll
        for (int g = 0; g < 4; ++g)
            #pragma unroll
            for (int t = 0; t < 2; ++t)
                acc[g][t] = __builtin_amdgcn_mfma_f32_16x16x32_bf16(a[g], b[t], acc[g][t], 0, 0, 0);
    }

    // ---- Phase 3: j-max. C layout: lane holds j-col n=lane&15, q-row m=(lane>>4)*4+reg.
    float vg[4][4];
    #pragma unroll
    for (int g = 0; g < 4; ++g)
        #pragma unroll
        for (int r = 0; r < 4; ++r)
            vg[g][r] = fmaxf(acc[g][0][r], acc[g][1][r]);
    #pragma unroll
    for (int off = 1; off < 16; off <<= 1)
        #pragma unroll
        for (int g = 0; g < 4; ++g)
            #pragma unroll
            for (int r = 0; r < 4; ++r)
                vg[g][r] = fmaxf(vg[g][r], __shfl_xor(vg[g][r], off, 64));

    if ((lane & 15) == 0) {
        int sgrp = lane >> 4;              // 0..3
        #pragma unroll
        for (int g = 0; g < 4; ++g)
            #pragma unroll
            for (int r = 0; r < 4; ++r)
                red[wv][g * 16 + sgrp * 4 + r] = vg[g][r];
    }
    __syncthreads();
    if (tid < QBLK) {
        float m = fmaxf(fmaxf(red[0][tid], red[1][tid]),
                        fmaxf(red[2][tid], red[3][tid]));
        pm[(size_t)(qblk * QBLK + tid) * NJB + jblk] = m;
    }

    // ---- Phase 4: last-block final reduction (rocPRIM pattern).
    __syncthreads();                       // pm stores issued by tid<64 complete
    __threadfence();                       // release pm to device scope
    if (tid == 0) {
        unsigned old = atomicAdd(cnt, 1u);
        isLast = (old == (unsigned)(NBLOCKS - 1));
    }
    __syncthreads();
    if (!isLast) return;

    __threadfence();                       // acquire: see all blocks' pm
    float psum = 0.0f;
    #pragma unroll
    for (int pass = 0; pass < 2; ++pass) {
        int q = tid + pass * 256;          // 0..511
        const float4* row = (const float4*)(pm + (size_t)q * NJB);  // 240B rows, 16B-aligned
        float vce = -1e30f, vch = -1e30f;
        #pragma unroll
        for (int c = 0; c < EASY_JB / 4; ++c) {        // cols 0..7
            float4 v = row[c];
            vce = fmaxf(fmaxf(vce, fmaxf(v.x, v.y)), fmaxf(v.z, v.w));
        }
        #pragma unroll
        for (int c = EASY_JB / 4; c < NJB / 4; ++c) {  // cols 8..59
            float4 v = row[c];
            vch = fmaxf(fmaxf(vch, fmaxf(v.x, v.y)), fmaxf(v.z, v.w));
        }
        float d = (vch - vce) * 10.0f;     // /SIGMA1
        psum += (d > 0.0f) ? (d + log1pf(expf(-d))) : log1pf(expf(d));  // stable softplus
    }
    #pragma unroll
    for (int off = 32; off > 0; off >>= 1) psum += __shfl_xor(psum, off, 64);
    if (lane == 0) wsum[wv] = psum;
    __syncthreads();
    if (tid == 0) {
        float s = wsum[0] + wsum[1] + wsum[2] + wsum[3];
        out[0] = a_in[0] * (s / (float)NQ);
    }
}

extern "C" void kernel_launch(void* const* d_in, const int* in_sizes, int n_in,
                              void* d_out, int out_size, void* d_ws, size_t ws_size,
                              hipStream_t stream) {
    const float* f = (const float*)d_in[0];
    // d_in[1] = Lvec (unused by the reference computation)
    const float* a = (const float*)d_in[2];

    float* pm = (float*)d_ws;                                  // 512*60 f32 = 120 KB
    unsigned* cnt = (unsigned*)((char*)d_ws + (size_t)NQ * NJB * sizeof(float));
    float* out = (float*)d_out;

    hipMemsetAsync(cnt, 0, sizeof(unsigned), stream);          // graph-legal memset node
    dim3 g(NJB, NQB);                                          // 60 x 8 = 480 blocks
    kmain<<<g, 256, 0, stream>>>(f, a, pm, cnt, out);
}

// Round 5
// 77.184 us; speedup vs baseline: 1.4536x; 1.4536x over previous
//
#include <hip/hip_runtime.h>
#include <hip/hip_bf16.h>
#include <math.h>

// Problem constants (fixed by setup_inputs)
constexpr int N   = 8192;
constexpr int D   = 128;
constexpr int IPC = 512;
constexpr int BZ  = 8192;
constexpr int Q0  = BZ - IPC;        // 7680: first query row
constexpr int NQ  = IPC;             // 512 queries
constexpr int JMAX = BZ - IPC;       // 7680 candidate cols [0,7680)
constexpr int JBLK = 128;            // j per block
constexpr int NJB  = JMAX / JBLK;    // 60
constexpr int EASY_JB = (2 * IPC) / JBLK;  // 8 -> jblk 0..7 easy ([0,1024)), 8..59 hard
constexpr int QBLK = 64;             // q per block
constexpr int NQB  = NQ / QBLK;      // 8
constexpr int NBLOCKS = NJB * NQB;   // 480
constexpr int RSTR = 136;            // LDS row stride in shorts (16B-aligned rows)
constexpr unsigned POISON   = 0xAAAAAAAAu;   // our own memset value for gm/cnt
constexpr unsigned ENC_BASE = 0xA0000000u;

typedef __attribute__((ext_vector_type(8))) short short8;   // 8 bf16 = 4 VGPRs
typedef __attribute__((ext_vector_type(4))) float f32x4;    // MFMA C/D

// Order-preserving encode for atomicMin with 0xAA-poison as identity:
// cos+2 in ~[0.9, 3.1] -> float bits in [0x3F66.., 0x4047..]; ENC_BASE - bits
// is ~[0x5FB9.., 0x609A..] < 0xAAAAAAAA, monotone DEcreasing in cos, exactly
// invertible. atomicMin keeps the largest cos; poison loses to everything.
__device__ __forceinline__ unsigned enc(float c) { return ENC_BASE - __float_as_uint(c + 2.0f); }
__device__ __forceinline__ float    dec(unsigned u) { return __uint_as_float(ENC_BASE - u) - 2.0f; }

// Fused: raw-bf16 LDS staging + norms + MFMA 64q x 128j + per-lane rj scaling +
// segmented j-max -> device-scope atomicMin -> last-block softplus reduction.
// All cross-block traffic is device-scope atomics (performed at LLC): NO
// __threadfence -> no L2 writeback/invalidate storms (the R4 regression).
__global__ __launch_bounds__(256) void kmain(const float* __restrict__ f,
                                             const float* __restrict__ a_in,
                                             unsigned* __restrict__ gm,   // [2*NQ]
                                             unsigned* __restrict__ cnt,
                                             unsigned* __restrict__ sink,
                                             float* __restrict__ out) {
    __shared__ __align__(16) short S[192 * RSTR];   // rows 0..63 = A(q), 64..191 = B(j)
    __shared__ float Rn[192];                        // reciprocal norms (fp32, exact)
    __shared__ float red[4][QBLK];
    __shared__ float wsum[4];
    __shared__ int isLast;

    const int tid  = threadIdx.x;
    const int lane = tid & 63;
    const int wv   = tid >> 6;
    const int jblk = blockIdx.x;           // 0..59
    const int qblk = blockIdx.y;           // 0..7

    // ---- Phase 1: load raw fp32 -> bf16 LDS (no normalize on the store path);
    // sum-of-squares into registers, shuffle chains AFTER the loop for ILP.
    {
        const int sub = tid & 15;          // element group: elems [8*sub, 8*sub+8)
        const int rof = tid >> 4;          // row-within-group-of-16
        float ssr[12];
        #pragma unroll
        for (int i = 0; i < 12; ++i) {
            int ridx = i * 16 + rof;       // 0..191
            int grow = (ridx < QBLK) ? (Q0 + qblk * QBLK + ridx)
                                     : (jblk * JBLK + (ridx - QBLK));
            const float* rp = f + (size_t)grow * D + sub * 8;
            float4 v0 = *(const float4*)(rp);
            float4 v1 = *(const float4*)(rp + 4);
            short8 h;
            {
                __hip_bfloat16 b;
                b = __float2bfloat16(v0.x); h[0] = *(short*)&b;
                b = __float2bfloat16(v0.y); h[1] = *(short*)&b;
                b = __float2bfloat16(v0.z); h[2] = *(short*)&b;
                b = __float2bfloat16(v0.w); h[3] = *(short*)&b;
                b = __float2bfloat16(v1.x); h[4] = *(short*)&b;
                b = __float2bfloat16(v1.y); h[5] = *(short*)&b;
                b = __float2bfloat16(v1.z); h[6] = *(short*)&b;
                b = __float2bfloat16(v1.w); h[7] = *(short*)&b;
            }
            *(short8*)&S[ridx * RSTR + sub * 8] = h;
            ssr[i] = v0.x*v0.x + v0.y*v0.y + v0.z*v0.z + v0.w*v0.w
                   + v1.x*v1.x + v1.y*v1.y + v1.z*v1.z + v1.w*v1.w;
        }
        #pragma unroll
        for (int off = 1; off < 16; off <<= 1)
            #pragma unroll
            for (int i = 0; i < 12; ++i) ssr[i] += __shfl_xor(ssr[i], off, 64);
        if (sub < 12) {
            int ridx = sub * 16 + rof;
            Rn[ridx] = 1.0f / fmaxf(sqrtf(ssr[sub]), 1e-12f);
        }
    }
    __syncthreads();

    // ---- Phase 2: MFMA on raw bf16. Wave wv owns j sub-range [wv*32, +32).
    const int row16 = lane & 15;
    const int kgrp  = lane >> 4;           // 0..3
    const short* As = S;
    const short* Bs = S + QBLK * RSTR + wv * 32 * RSTR;

    f32x4 acc[4][2] = {};  // [q-group g][j-tile t]
    #pragma unroll
    for (int c = 0; c < 4; ++c) {          // k-chunks of 32
        const int ko = c * 32 + kgrp * 8;
        short8 a[4], b[2];
        #pragma unroll
        for (int g = 0; g < 4; ++g)
            a[g] = *(const short8*)(As + (g * 16 + row16) * RSTR + ko);
        #pragma unroll
        for (int t = 0; t < 2; ++t)
            b[t] = *(const short8*)(Bs + (t * 16 + row16) * RSTR + ko);
        #pragma unroll
        for (int g = 0; g < 4; ++g)
            #pragma unroll
            for (int t = 0; t < 2; ++t)
                acc[g][t] = __builtin_amdgcn_mfma_f32_16x16x32_bf16(a[g], b[t], acc[g][t], 0, 0, 0);
    }

    // ---- Phase 3: scale by rnorm[j] (per-lane: col = lane&15), j-max, then
    // rnorm[q] at the write. C layout: col(j)=lane&15, row(q)=(lane>>4)*4+reg.
    float rj0 = Rn[QBLK + wv * 32 + row16];
    float rj1 = Rn[QBLK + wv * 32 + 16 + row16];
    float vg[4][4];
    #pragma unroll
    for (int g = 0; g < 4; ++g)
        #pragma unroll
        for (int r = 0; r < 4; ++r)
            vg[g][r] = fmaxf(acc[g][0][r] * rj0, acc[g][1][r] * rj1);
    #pragma unroll
    for (int off = 1; off < 16; off <<= 1)
        #pragma unroll
        for (int g = 0; g < 4; ++g)
            #pragma unroll
            for (int r = 0; r < 4; ++r)
                vg[g][r] = fmaxf(vg[g][r], __shfl_xor(vg[g][r], off, 64));

    if ((lane & 15) == 0) {
        int sgrp = lane >> 4;              // 0..3
        #pragma unroll
        for (int g = 0; g < 4; ++g)
            #pragma unroll
            for (int r = 0; r < 4; ++r)
                red[wv][g * 16 + sgrp * 4 + r] = vg[g][r];
    }
    __syncthreads();
    if (tid < QBLK) {
        float m = fmaxf(fmaxf(red[0][tid], red[1][tid]),
                        fmaxf(red[2][tid], red[3][tid]));
        float cosv = m * Rn[tid];          // rnorm[q] > 0: commutes with max
        int sel = (jblk < EASY_JB) ? 0 : 1;
        // Returning atomic: vmcnt tracks completion at the coherence point.
        unsigned old = atomicMin(&gm[sel * NQ + qblk * QBLK + tid], enc(cosv));
        if (old == 1u) sink[0] = old;      // consume return (never true)
    }

    // ---- Phase 4: last-block reduction, atomic-only (no fences).
    __builtin_amdgcn_s_waitcnt(0);         // belt&suspenders: drain this wave's atomics
    __syncthreads();                       // barrier implies vmcnt(0) for all waves
    if (tid == 0) {
        unsigned old = atomicAdd(cnt, 1u);
        isLast = (old == POISON + (unsigned)(NBLOCKS - 1));
    }
    __syncthreads();
    if (!isLast) return;

    float psum = 0.0f;
    #pragma unroll
    for (int p = 0; p < 2; ++p) {
        int q = tid + p * 256;             // 0..511
        unsigned ue = __hip_atomic_load(&gm[q],      __ATOMIC_RELAXED, __HIP_MEMORY_SCOPE_AGENT);
        unsigned uh = __hip_atomic_load(&gm[NQ + q], __ATOMIC_RELAXED, __HIP_MEMORY_SCOPE_AGENT);
        float d = (dec(uh) - dec(ue)) * 10.0f;   // (VCH - VCE)/SIGMA1
        psum += (d > 0.0f) ? (d + log1pf(expf(-d))) : log1pf(expf(d));  // stable softplus
    }
    #pragma unroll
    for (int off = 32; off > 0; off >>= 1) psum += __shfl_xor(psum, off, 64);
    if (lane == 0) wsum[wv] = psum;
    __syncthreads();
    if (tid == 0) {
        float s = wsum[0] + wsum[1] + wsum[2] + wsum[3];
        out[0] = a_in[0] * (s / (float)NQ);
    }
}

extern "C" void kernel_launch(void* const* d_in, const int* in_sizes, int n_in,
                              void* d_out, int out_size, void* d_ws, size_t ws_size,
                              hipStream_t stream) {
    const float* f = (const float*)d_in[0];
    // d_in[1] = Lvec (unused by the reference computation)
    const float* a = (const float*)d_in[2];

    unsigned* gm   = (unsigned*)d_ws;                      // 2*512 u32 = 4096 B
    unsigned* cnt  = gm + 2 * NQ;                          // +4096
    unsigned* sink = cnt + 1;                              // +4100
    float* out = (float*)d_out;

    // Poison gm/cnt ourselves (graph-legal memset node): gm identity for the
    // atomicMin encoding, cnt start value for the last-block detector.
    hipMemsetAsync(gm, 0xAA, (2 * NQ + 2) * sizeof(unsigned), stream);
    dim3 g(NJB, NQB);                                      // 60 x 8 = 480 blocks
    kmain<<<g, 256, 0, stream>>>(f, a, gm, cnt, sink, out);
}

// Round 6
// 73.577 us; speedup vs baseline: 1.5249x; 1.0490x over previous
//
#include <hip/hip_runtime.h>
#include <hip/hip_bf16.h>
#include <math.h>

// Problem constants (fixed by setup_inputs)
constexpr int N   = 8192;
constexpr int D   = 128;
constexpr int IPC = 512;
constexpr int BZ  = 8192;
constexpr int Q0  = BZ - IPC;        // 7680: first query row
constexpr int NQ  = IPC;             // 512 queries
constexpr int JMAX = BZ - IPC;       // 7680 candidate cols [0,7680)
constexpr int JBLK = 128;            // j per block
constexpr int NJB  = JMAX / JBLK;    // 60
constexpr int EASY_JB = (2 * IPC) / JBLK;  // 8 -> jblk 0..7 easy ([0,1024)), 8..59 hard
constexpr int QBLK = 64;             // q per block
constexpr int NQB  = NQ / QBLK;      // 8
constexpr int RSTR = 136;            // LDS row stride in shorts (272 B: 16B-aligned, 68 words = 4 mod 32 banks)

typedef __attribute__((ext_vector_type(8))) short short8;   // 8 bf16 = 4 VGPRs
typedef __attribute__((ext_vector_type(4))) float f32x4;    // MFMA C/D

// K1: raw-bf16 LDS staging + register SS + MFMA 64q x 128j + epilogue norms + j-max.
// grid (NJB, NQB), 256 threads = 4 waves. Plain global stores of per-(q,jblk) maxes;
// no cross-block sync (R4's fences and R5's atomics both regressed).
__global__ __launch_bounds__(256, 2) void kmain(const float* __restrict__ f,
                                                float* __restrict__ pm) {
    __shared__ __align__(16) short S[192 * RSTR];   // rows 0..63 = A(q), 64..191 = B(j); 51 KB
    __shared__ float Rn[192];                        // reciprocal norms (fp32, exact)
    __shared__ float red[4][QBLK];

    const int tid  = threadIdx.x;
    const int lane = tid & 63;
    const int wv   = tid >> 6;
    const int jblk = blockIdx.x;           // 0..59
    const int qblk = blockIdx.y;           // 0..7

    // ---- Phase 1: fp32 -> raw bf16 LDS (packed cvt, no normalize on store path);
    // sum-of-squares in registers, shuffle chains after the loop for ILP.
    {
        const int sub = tid & 15;          // element group: elems [8*sub, 8*sub+8)
        const int rof = tid >> 4;          // row-within-group-of-16
        float ssr[12];
        #pragma unroll
        for (int i = 0; i < 12; ++i) {
            int ridx = i * 16 + rof;       // 0..191
            int grow = (ridx < QBLK) ? (Q0 + qblk * QBLK + ridx)
                                     : (jblk * JBLK + (ridx - QBLK));
            const float* rp = f + (size_t)grow * D + sub * 8;
            float4 v0 = *(const float4*)(rp);
            float4 v1 = *(const float4*)(rp + 4);
            __hip_bfloat162 b0 = __float22bfloat162_rn({v0.x, v0.y});
            __hip_bfloat162 b1 = __float22bfloat162_rn({v0.z, v0.w});
            __hip_bfloat162 b2 = __float22bfloat162_rn({v1.x, v1.y});
            __hip_bfloat162 b3 = __float22bfloat162_rn({v1.z, v1.w});
            uint4 hw;
            hw.x = *(unsigned*)&b0;
            hw.y = *(unsigned*)&b1;
            hw.z = *(unsigned*)&b2;
            hw.w = *(unsigned*)&b3;
            *(uint4*)&S[ridx * RSTR + sub * 8] = hw;
            ssr[i] = v0.x*v0.x + v0.y*v0.y + v0.z*v0.z + v0.w*v0.w
                   + v1.x*v1.x + v1.y*v1.y + v1.z*v1.z + v1.w*v1.w;
        }
        #pragma unroll
        for (int off = 1; off < 16; off <<= 1)
            #pragma unroll
            for (int i = 0; i < 12; ++i) ssr[i] += __shfl_xor(ssr[i], off, 64);
        if (sub < 12) {
            int ridx = sub * 16 + rof;
            Rn[ridx] = 1.0f / fmaxf(sqrtf(ssr[sub]), 1e-12f);
        }
    }
    __syncthreads();

    // ---- Phase 2: MFMA on raw bf16. Wave wv owns j sub-range [wv*32, +32).
    // 16x16x32 operand layout: lane l holds row (l&15), k = (l>>4)*8..+7.
    const int row16 = lane & 15;
    const int kgrp  = lane >> 4;           // 0..3
    const short* As = S;
    const short* Bs = S + QBLK * RSTR + wv * 32 * RSTR;

    f32x4 acc[4][2] = {};  // [q-group g][j-tile t]
    #pragma unroll
    for (int c = 0; c < 4; ++c) {          // k-chunks of 32
        const int ko = c * 32 + kgrp * 8;
        short8 a[4], b[2];
        #pragma unroll
        for (int g = 0; g < 4; ++g)
            a[g] = *(const short8*)(As + (g * 16 + row16) * RSTR + ko);
        #pragma unroll
        for (int t = 0; t < 2; ++t)
            b[t] = *(const short8*)(Bs + (t * 16 + row16) * RSTR + ko);
        #pragma unroll
        for (int g = 0; g < 4; ++g)
            #pragma unroll
            for (int t = 0; t < 2; ++t)
                acc[g][t] = __builtin_amdgcn_mfma_f32_16x16x32_bf16(a[g], b[t], acc[g][t], 0, 0, 0);
    }

    // ---- Phase 3: scale by rnorm[j] (per-lane: col = lane&15), j-max across lanes,
    // rnorm[q] at the write (positive scaling commutes with max).
    // C layout: col(j)=lane&15, row(q)=(lane>>4)*4+reg.
    float rj0 = Rn[QBLK + wv * 32 + row16];
    float rj1 = Rn[QBLK + wv * 32 + 16 + row16];
    float vg[4][4];
    #pragma unroll
    for (int g = 0; g < 4; ++g)
        #pragma unroll
        for (int r = 0; r < 4; ++r)
            vg[g][r] = fmaxf(acc[g][0][r] * rj0, acc[g][1][r] * rj1);
    #pragma unroll
    for (int off = 1; off < 16; off <<= 1)
        #pragma unroll
        for (int g = 0; g < 4; ++g)
            #pragma unroll
            for (int r = 0; r < 4; ++r)
                vg[g][r] = fmaxf(vg[g][r], __shfl_xor(vg[g][r], off, 64));

    if ((lane & 15) == 0) {
        int sgrp = lane >> 4;              // 0..3
        #pragma unroll
        for (int g = 0; g < 4; ++g)
            #pragma unroll
            for (int r = 0; r < 4; ++r)
                red[wv][g * 16 + sgrp * 4 + r] = vg[g][r];
    }
    __syncthreads();
    if (tid < QBLK) {
        float m = fmaxf(fmaxf(red[0][tid], red[1][tid]),
                        fmaxf(red[2][tid], red[3][tid]));
        pm[(size_t)(qblk * QBLK + tid) * NJB + jblk] = m * Rn[tid];
    }
}

// K2: final loss. pm rows are 240 B (16B-aligned) -> float4 reads.
__global__ __launch_bounds__(512) void kfinal(const float* __restrict__ pm,
                                              const float* __restrict__ a_in,
                                              float* __restrict__ out) {
    __shared__ float wsum[8];
    int q = threadIdx.x;  // 0..511
    const float4* row = (const float4*)(pm + (size_t)q * NJB);
    float vce = -1e30f, vch = -1e30f;
    #pragma unroll
    for (int c = 0; c < EASY_JB / 4; ++c) {        // cols 0..7 (easy)
        float4 v = row[c];
        vce = fmaxf(fmaxf(vce, fmaxf(v.x, v.y)), fmaxf(v.z, v.w));
    }
    #pragma unroll
    for (int c = EASY_JB / 4; c < NJB / 4; ++c) {  // cols 8..59 (hard)
        float4 v = row[c];
        vch = fmaxf(fmaxf(vch, fmaxf(v.x, v.y)), fmaxf(v.z, v.w));
    }
    float d = (vch - vce) * 10.0f;  // /SIGMA1
    float p = (d > 0.0f) ? (d + log1pf(expf(-d))) : log1pf(expf(d));  // stable softplus
    #pragma unroll
    for (int off = 32; off > 0; off >>= 1) p += __shfl_xor(p, off, 64);
    int lane = q & 63, w = q >> 6;
    if (lane == 0) wsum[w] = p;
    __syncthreads();
    if (q == 0) {
        float s = 0.0f;
        #pragma unroll
        for (int i = 0; i < 8; ++i) s += wsum[i];
        out[0] = a_in[0] * (s / (float)NQ);
    }
}

extern "C" void kernel_launch(void* const* d_in, const int* in_sizes, int n_in,
                              void* d_out, int out_size, void* d_ws, size_t ws_size,
                              hipStream_t stream) {
    const float* f = (const float*)d_in[0];
    // d_in[1] = Lvec (unused by the reference computation)
    const float* a = (const float*)d_in[2];

    float* pm  = (float*)d_ws;             // 512*60 f32 = 120 KB
    float* out = (float*)d_out;

    dim3 g(NJB, NQB);                      // 60 x 8 = 480 blocks
    kmain<<<g, 256, 0, stream>>>(f, pm);
    kfinal<<<1, 512, 0, stream>>>(pm, a, out);
}